// Round 18
// baseline (946.594 us; speedup 1.0000x reference)
//
#include <hip/hip_runtime.h>
#include <hip/hip_bf16.h>
#include <math.h>

typedef __attribute__((ext_vector_type(8))) short bf16x8;
typedef __attribute__((ext_vector_type(4))) short bf16x4;
typedef __attribute__((ext_vector_type(4))) float f32x4;
typedef __hip_bfloat16 bf16;

#define NH 12
#define HD 32
#define NPAD 64
#define NWIN 2048
#define NTOK 100352
#define HBLK (NPAD*HD)
#define WBLK (3*NH*HBLK)

typedef __attribute__((address_space(3))) const void cv3;

#define STR2(x) #x
#define DSR(dst, base, OFF)                                                  \
  asm volatile("ds_read_b128 %0, %1 offset:" STR2(OFF)                       \
               : "=v"(dst) : "v"(base))

__device__ inline float wave_sum(float v) {
#pragma unroll
  for (int off = 32; off; off >>= 1) v += __shfl_xor(v, off);
  return v;
}

__device__ inline void load_lds16(const bf16* g, bf16* l) {
  __builtin_amdgcn_global_load_lds((const __attribute__((address_space(1))) void*)g,
                                   (__attribute__((address_space(3))) void*)l, 16, 0, 0);
}

__device__ inline short bfbits(float f) {
  bf16 h = __float2bfloat16(f);
  return *(short*)&h;
}

// tanh-form GELU via hardware exp: g = x*e/(e+1), e = exp(1.59576912*(x+0.044715 x^3)).
// Max dev vs erf-GELU ~3e-3; arg clamped to avoid inf/inf.
__device__ inline float gelu_fast(float x) {
  float u = x + 0.044715f * x * x * x;
  float a = fminf(1.5957691216057308f * u, 80.0f);
  float e = __expf(a);
  return x * e / (e + 1.0f);
}

// ---------------- weight cast + transpose
__global__ __launch_bounds__(256) void cast_transpose(const float* __restrict__ in,
                                                      bf16* __restrict__ out, int K, int N) {
  int e = blockIdx.x * 256 + threadIdx.x;
  if (e >= K * N) return;
  int n = e / K, k = e - n * K;
  out[e] = __float2bfloat16(in[k * N + n]);
}

// ---------------- zero the 15 pad rows of every (w, which, h) QKV block
__global__ __launch_bounds__(256) void zero_pads(bf16* __restrict__ qkv) {
  int idx = blockIdx.x * 256 + threadIdx.x;
  const int total = NWIN * 3 * NH * 15 * HD;
  if (idx >= total) return;
  int d = idx & 31; int rest = idx >> 5;
  int n = 49 + (rest % 15); rest /= 15;
  int h = rest % NH; rest /= NH;
  int which = rest % 3; int w = rest / 3;
  size_t base = (size_t)w * WBLK + (size_t)which * NH * HBLK + (size_t)h * HBLK;
  size_t addr = (which == 2) ? base + (size_t)d * NPAD + n : base + (size_t)n * HD + d;
  qkv[addr] = __float2bfloat16(0.0f);
}

// ---------------- bias+mask table: tbl[cls][h][row][64]
__global__ __launch_bounds__(256) void build_bias(const float* __restrict__ rel,
                                                  float* __restrict__ tbl) {
  int e = blockIdx.x * 256 + threadIdx.x;
  if (e >= 4 * 12 * 49 * 64) return;
  int col = e & 63; int t = e >> 6;
  int row = t % 49; t /= 49;
  int h = t % 12; int cls = t / 12;
  float v;
  if (col >= 49) {
    v = -1e30f;
  } else {
    int py = row / 7, px = row - py * 7;
    int qy = col / 7, qx = col - qy * 7;
    int ridx = (py - qy + 6) * 13 + (px - qx + 6);
    v = rel[ridx * 12 + h];
    int wy7 = cls >> 1, wx7 = cls & 1;
    int ly_r = wy7 ? (py < 4 ? 1 : 2) : 0;
    int lx_r = wx7 ? (px < 4 ? 1 : 2) : 0;
    int ly_c = wy7 ? (qy < 4 ? 1 : 2) : 0;
    int lx_c = wx7 ? (qx < 4 ? 1 : 2) : 0;
    if ((ly_r * 3 + lx_r) != (ly_c * 3 + lx_c)) v += -100.0f;
  }
  tbl[e] = v;
}

// ---------------- LayerNorm
template <int MODE>
__global__ __launch_bounds__(256) void ln_kernel(const float* __restrict__ x,
                                                 const float* __restrict__ g,
                                                 const float* __restrict__ be,
                                                 bf16* __restrict__ out) {
  int wv = threadIdx.x >> 6, lane = threadIdx.x & 63;
  int t = blockIdx.x * 4 + wv;
  size_t src;
  if (MODE == 0) {
    int w = t / 49, n = t - w * 49;
    int b = w >> 6, wi = w & 63;
    int wy = wi >> 3, wx = wi & 7;
    int py = n / 7, px = n - py * 7;
    int rr = wy * 7 + py, cc = wx * 7 + px;
    int ro = rr + 3; if (ro >= 56) ro -= 56;
    int co = cc + 3; if (co >= 56) co -= 56;
    src = (size_t)b * 3136 + ro * 56 + co;
  } else {
    src = (size_t)t;
  }
  const float2* row2 = (const float2*)(x + src * 384);
  float2 v[3]; float s = 0.f;
#pragma unroll
  for (int j = 0; j < 3; ++j) { v[j] = row2[lane + 64 * j]; s += v[j].x + v[j].y; }
  s = wave_sum(s);
  float mu = s * (1.f / 384.f);
  float q = 0.f;
#pragma unroll
  for (int j = 0; j < 3; ++j) {
    float dx = v[j].x - mu, dy = v[j].y - mu;
    q += dx * dx + dy * dy;
  }
  q = wave_sum(q);
  float rs = rsqrtf(q * (1.f / 384.f) + 1e-5f);
  uint* o = (uint*)(out + (size_t)t * 384);
  const float2* g2 = (const float2*)g;
  const float2* b2 = (const float2*)be;
#pragma unroll
  for (int j = 0; j < 3; ++j) {
    int c2 = lane + 64 * j;
    float2 gg = g2[c2], bb = b2[c2];
    float ox = (v[j].x - mu) * rs * gg.x + bb.x;
    float oy = (v[j].y - mu) * rs * gg.y + bb.y;
    o[c2] = (uint)(unsigned short)bfbits(ox) | ((uint)(unsigned short)bfbits(oy) << 16);
  }
}

// ---------------- GEMM for K=384 layers (R16 structure, best measured for L3-warm A):
// 128x128, 4 waves, BK=32, 2-stage ring = 32 KB, per-iter vmcnt(0) covered by 4 blocks/CU.
// EPI: 0=QKV scatter, 1=proj+residual+reverse, 2=fastGELU->h1
template <int EPI>
__global__ __launch_bounds__(256, 4) void gemm128(const bf16* __restrict__ A,
                                                  const bf16* __restrict__ BT,
                                                  int K, int NCOL, int row0,
                                                  const float* __restrict__ bias,
                                                  const float* __restrict__ extra,
                                                  void* __restrict__ outp) {
  __shared__ __align__(16) bf16 As[2][128 * 32];
  __shared__ __align__(16) bf16 Bs[2][128 * 32];
  int tid = threadIdx.x, lane = tid & 63, wv = tid >> 6;
  int wr = wv >> 1, wc = wv & 1;
  int lr = lane & 15, lg = lane >> 4;

  int nwg = gridDim.x;
  int bid = blockIdx.x;
  int xcd = bid & 7, li = bid >> 3;
  int qq = nwg >> 3, rr8 = nwg & 7;
  int start = xcd * qq + (xcd < rr8 ? xcd : rr8);
  int lin = start + li;
  int brow = lin / NCOL, bcol = lin - brow * NCOL;

  const bf16* Ab = A + (size_t)brow * 128 * K;
  const bf16* Bb = BT + (size_t)bcol * 128 * K;

  int srow = lane >> 2;
  int scol8 = (((lane & 3) ^ ((srow >> 1) & 3)) << 3);
  const bf16* aS = Ab + (size_t)(wv * 32 + srow) * K + scol8;
  const bf16* bS = Bb + (size_t)(wv * 32 + srow) * K + scol8;

  f32x4 acc[4][4] = {};
  int nk = K >> 5;
  int koff = ((lg ^ ((lr >> 1) & 3)) << 3);

#define STAGE(buf)                                                            \
  {                                                                           \
    load_lds16(aS, &As[buf][wv * 1024]);                                      \
    load_lds16(aS + (size_t)16 * K, &As[buf][wv * 1024 + 512]);               \
    load_lds16(bS, &Bs[buf][wv * 1024]);                                      \
    load_lds16(bS + (size_t)16 * K, &Bs[buf][wv * 1024 + 512]);               \
    aS += 32; bS += 32;                                                       \
  }

  STAGE(0);
  asm volatile("s_waitcnt vmcnt(0)" ::: "memory");
  __builtin_amdgcn_s_barrier();

  for (int it = 0; it < nk; ++it) {
    int buf = it & 1;
    if (it + 1 < nk) STAGE(buf ^ 1);
    cv3* pA = (cv3*)&As[buf][(wr * 64 + lr) * 32 + koff];
    cv3* pB = (cv3*)&Bs[buf][(wc * 64 + lr) * 32 + koff];
    bf16x8 a[4], b[4];
    DSR(a[0], pA, 0);
    DSR(b[0], pB, 0); DSR(b[1], pB, 1024); DSR(b[2], pB, 2048); DSR(b[3], pB, 3072);
    DSR(a[1], pA, 1024); DSR(a[2], pA, 2048); DSR(a[3], pA, 3072);
    asm volatile("s_waitcnt lgkmcnt(3)" ::: "memory");
    __builtin_amdgcn_sched_barrier(0);
    __builtin_amdgcn_s_setprio(1);
#pragma unroll
    for (int j = 0; j < 4; ++j)
      acc[0][j] = __builtin_amdgcn_mfma_f32_16x16x32_bf16(b[j], a[0], acc[0][j], 0, 0, 0);
    __builtin_amdgcn_s_setprio(0);
    asm volatile("s_waitcnt lgkmcnt(0)" ::: "memory");
    __builtin_amdgcn_sched_barrier(0);
    __builtin_amdgcn_s_setprio(1);
#pragma unroll
    for (int i = 1; i < 4; ++i)
#pragma unroll
      for (int j = 0; j < 4; ++j)
        acc[i][j] = __builtin_amdgcn_mfma_f32_16x16x32_bf16(b[j], a[i], acc[i][j], 0, 0, 0);
    __builtin_amdgcn_s_setprio(0);
    if (it + 1 < nk) {
      asm volatile("s_waitcnt vmcnt(0)" ::: "memory");
      __builtin_amdgcn_s_barrier();
    }
  }
#undef STAGE

  float4 bias4[4];
#pragma unroll
  for (int j = 0; j < 4; ++j)
    bias4[j] = *(const float4*)(bias + bcol * 128 + wc * 64 + j * 16 + lg * 4);

#pragma unroll
  for (int i = 0; i < 4; ++i) {
    int lrow = brow * 128 + wr * 64 + i * 16 + lr;
    int grow = row0 + lrow;
    int w_ = 0, n_ = 0; size_t tok = 0;
    if (EPI == 0 || EPI == 1) {
      w_ = grow / 49; n_ = grow - w_ * 49;
      if (EPI == 1) {
        int b_ = w_ >> 6, wi = w_ & 63;
        int wy = wi >> 3, wx = wi & 7;
        int py = n_ / 7, px = n_ - py * 7;
        int r2 = wy * 7 + py, c2 = wx * 7 + px;
        int ro = r2 + 3; if (ro >= 56) ro -= 56;
        int co = c2 + 3; if (co >= 56) co -= 56;
        tok = (size_t)b_ * 3136 + ro * 56 + co;
      }
    }
#pragma unroll
    for (int j = 0; j < 4; ++j) {
      int col = bcol * 128 + wc * 64 + j * 16 + lg * 4;
      float v0 = acc[i][j][0] + bias4[j].x;
      float v1 = acc[i][j][1] + bias4[j].y;
      float v2 = acc[i][j][2] + bias4[j].z;
      float v3 = acc[i][j][3] + bias4[j].w;
      if (EPI == 0) {
        int which = (col >= 768) ? 2 : (col >= 384 ? 1 : 0);
        int cc = col - which * 384;
        int hh = cc >> 5, d0 = cc & 31;
        size_t base = (size_t)w_ * WBLK + (size_t)which * NH * HBLK + (size_t)hh * HBLK;
        if (which == 2) {
          bf16* vp = (bf16*)outp + base + (size_t)d0 * NPAD + n_;
          vp[0] = __float2bfloat16(v0);
          vp[NPAD] = __float2bfloat16(v1);
          vp[2 * NPAD] = __float2bfloat16(v2);
          vp[3 * NPAD] = __float2bfloat16(v3);
        } else {
          bf16x4 p = {bfbits(v0), bfbits(v1), bfbits(v2), bfbits(v3)};
          *(bf16x4*)((bf16*)outp + base + (size_t)n_ * HD + d0) = p;
        }
      } else if (EPI == 1) {
        size_t oidx = tok * 384 + col;
        float4 e = *(const float4*)(extra + oidx);
        float4 o = {v0 + e.x, v1 + e.y, v2 + e.z, v3 + e.w};
        *(float4*)((float*)outp + oidx) = o;
      } else {
        bf16x4 p = {bfbits(gelu_fast(v0)), bfbits(gelu_fast(v1)),
                    bfbits(gelu_fast(v2)), bfbits(gelu_fast(v3))};
        *(bf16x4*)((bf16*)outp + (size_t)lrow * 1536 + col) = p;
      }
    }
  }
}

// ---------------- 3-STAGE GEMM for MLP2 (K=1536, streaming HBM-cold A = h1): counted
// vmcnt(4) pipeline, 48 KB, 3 blocks/CU. EPI fixed: out = acc + b2 + x1 -> d_out.
__global__ __launch_bounds__(256, 3) void gemm3s(const bf16* __restrict__ A,
                                                 const bf16* __restrict__ BT,
                                                 int K, int NCOL, int row0,
                                                 const float* __restrict__ bias,
                                                 const float* __restrict__ extra,
                                                 float* __restrict__ outp) {
  __shared__ __align__(16) bf16 As[3][128 * 32];
  __shared__ __align__(16) bf16 Bs[3][128 * 32];
  int tid = threadIdx.x, lane = tid & 63, wv = tid >> 6;
  int wr = wv >> 1, wc = wv & 1;
  int lr = lane & 15, lg = lane >> 4;

  int nwg = gridDim.x;
  int bid = blockIdx.x;
  int xcd = bid & 7, li = bid >> 3;
  int qq = nwg >> 3, rr8 = nwg & 7;
  int start = xcd * qq + (xcd < rr8 ? xcd : rr8);
  int lin = start + li;
  int brow = lin / NCOL, bcol = lin - brow * NCOL;

  const bf16* Ab = A + (size_t)brow * 128 * K;
  const bf16* Bb = BT + (size_t)bcol * 128 * K;

  int srow = lane >> 2;
  int scol8 = (((lane & 3) ^ ((srow >> 1) & 3)) << 3);
  const bf16* aS = Ab + (size_t)(wv * 32 + srow) * K + scol8;
  const bf16* bS = Bb + (size_t)(wv * 32 + srow) * K + scol8;

  f32x4 acc[4][4] = {};
  int nk = K >> 5;
  int koff = ((lg ^ ((lr >> 1) & 3)) << 3);

#define STAGE3(buf)                                                           \
  {                                                                           \
    load_lds16(aS, &As[buf][wv * 1024]);                                      \
    load_lds16(aS + (size_t)16 * K, &As[buf][wv * 1024 + 512]);               \
    load_lds16(bS, &Bs[buf][wv * 1024]);                                      \
    load_lds16(bS + (size_t)16 * K, &Bs[buf][wv * 1024 + 512]);               \
    aS += 32; bS += 32;                                                       \
  }

  STAGE3(0);
  STAGE3(1);
  asm volatile("s_waitcnt vmcnt(4)" ::: "memory");
  __builtin_amdgcn_s_barrier();

  for (int it = 0; it < nk; ++it) {
    int buf = it % 3;
    if (it + 2 < nk) STAGE3((it + 2) % 3);
    cv3* pA = (cv3*)&As[buf][(wr * 64 + lr) * 32 + koff];
    cv3* pB = (cv3*)&Bs[buf][(wc * 64 + lr) * 32 + koff];
    bf16x8 a[4], b[4];
    DSR(a[0], pA, 0);
    DSR(b[0], pB, 0); DSR(b[1], pB, 1024); DSR(b[2], pB, 2048); DSR(b[3], pB, 3072);
    DSR(a[1], pA, 1024); DSR(a[2], pA, 2048); DSR(a[3], pA, 3072);
    asm volatile("s_waitcnt lgkmcnt(3)" ::: "memory");
    __builtin_amdgcn_sched_barrier(0);
    __builtin_amdgcn_s_setprio(1);
#pragma unroll
    for (int j = 0; j < 4; ++j)
      acc[0][j] = __builtin_amdgcn_mfma_f32_16x16x32_bf16(b[j], a[0], acc[0][j], 0, 0, 0);
    __builtin_amdgcn_s_setprio(0);
    asm volatile("s_waitcnt lgkmcnt(0)" ::: "memory");
    __builtin_amdgcn_sched_barrier(0);
    __builtin_amdgcn_s_setprio(1);
#pragma unroll
    for (int i = 1; i < 4; ++i)
#pragma unroll
      for (int j = 0; j < 4; ++j)
        acc[i][j] = __builtin_amdgcn_mfma_f32_16x16x32_bf16(b[j], a[i], acc[i][j], 0, 0, 0);
    __builtin_amdgcn_s_setprio(0);
    if (it + 1 < nk) {
      if (it + 2 < nk)
        asm volatile("s_waitcnt vmcnt(4)" ::: "memory");
      else
        asm volatile("s_waitcnt vmcnt(0)" ::: "memory");
      __builtin_amdgcn_s_barrier();
    }
  }
#undef STAGE3

  float4 bias4[4];
#pragma unroll
  for (int j = 0; j < 4; ++j)
    bias4[j] = *(const float4*)(bias + bcol * 128 + wc * 64 + j * 16 + lg * 4);

#pragma unroll
  for (int i = 0; i < 4; ++i) {
    int grow = row0 + brow * 128 + wr * 64 + i * 16 + lr;
#pragma unroll
    for (int j = 0; j < 4; ++j) {
      int col = bcol * 128 + wc * 64 + j * 16 + lg * 4;
      size_t oidx = (size_t)grow * 384 + col;
      float4 e = *(const float4*)(extra + oidx);
      float4 o = {acc[i][j][0] + bias4[j].x + e.x, acc[i][j][1] + bias4[j].y + e.y,
                  acc[i][j][2] + bias4[j].z + e.z, acc[i][j][3] + bias4[j].w + e.w};
      *(float4*)(outp + oidx) = o;
    }
  }
}

// ---------------- windowed attention: 1 block per window, 4 waves x 3 heads.
__global__ __launch_bounds__(256) void attn_kernel(const bf16* __restrict__ qkv,
                                                   const float* __restrict__ tbl,
                                                   bf16* __restrict__ attn_out) {
  __shared__ __align__(16) bf16 P[4][64 * 72];
  int wv = threadIdx.x >> 6, lane = threadIdx.x & 63;
  int lr = lane & 15, lg = lane >> 4;
  int w = blockIdx.x;
  int wi = w & 63, wy = wi >> 3, wx = wi & 7;
  int cls = ((wy == 7) ? 2 : 0) | ((wx == 7) ? 1 : 0);
  const bf16* base = qkv + (size_t)w * WBLK;
  bf16* Pl = &P[wv][0];
  const float scale = 0.17677669529663689f;

  for (int hh = 0; hh < 3; ++hh) {
    int h = wv + hh * 4;
    const bf16* Q  = base + (size_t)h * HBLK;
    const bf16* Kp = base + (size_t)(NH + h) * HBLK;
    const bf16* Vt = base + (size_t)(2 * NH + h) * HBLK;
    const float* tb = tbl + (size_t)(cls * 12 + h) * 49 * 64;

    bf16x8 qa[4], kb[4];
#pragma unroll
    for (int t = 0; t < 4; ++t) {
      qa[t] = *(const bf16x8*)(Q  + (t * 16 + lr) * 32 + lg * 8);
      kb[t] = *(const bf16x8*)(Kp + (t * 16 + lr) * 32 + lg * 8);
    }
    f32x4 S[4][4] = {};
#pragma unroll
    for (int i = 0; i < 4; ++i)
#pragma unroll
      for (int j = 0; j < 4; ++j)
        S[i][j] = __builtin_amdgcn_mfma_f32_16x16x32_bf16(qa[i], kb[j], S[i][j], 0, 0, 0);

#pragma unroll
    for (int i = 0; i < 4; ++i) {
#pragma unroll
      for (int r = 0; r < 4; ++r) {
        int row = i * 16 + lg * 4 + r;
        const float* trow = tb + (row < 49 ? row : 0) * 64;
        float sv[4]; float m = -1e30f;
#pragma unroll
        for (int j = 0; j < 4; ++j) {
          float s = S[i][j][r] * scale + trow[j * 16 + lr];
          sv[j] = s;
          m = fmaxf(m, s);
        }
        m = fmaxf(m, __shfl_xor(m, 1));
        m = fmaxf(m, __shfl_xor(m, 2));
        m = fmaxf(m, __shfl_xor(m, 4));
        m = fmaxf(m, __shfl_xor(m, 8));
        float ev[4]; float sum = 0.f;
#pragma unroll
        for (int j = 0; j < 4; ++j) { ev[j] = __expf(sv[j] - m); sum += ev[j]; }
        sum += __shfl_xor(sum, 1);
        sum += __shfl_xor(sum, 2);
        sum += __shfl_xor(sum, 4);
        sum += __shfl_xor(sum, 8);
        float inv = 1.0f / sum;
#pragma unroll
        for (int j = 0; j < 4; ++j)
          Pl[row * 72 + j * 16 + lr] = __float2bfloat16(ev[j] * inv);
      }
    }

    bf16x8 vb[2][2];
#pragma unroll
    for (int kt = 0; kt < 2; ++kt)
#pragma unroll
      for (int cj = 0; cj < 2; ++cj)
        vb[kt][cj] = *(const bf16x8*)(Vt + (cj * 16 + lr) * 64 + kt * 32 + lg * 8);
    f32x4 O[4][2] = {};
#pragma unroll
    for (int i = 0; i < 4; ++i) {
#pragma unroll
      for (int kt = 0; kt < 2; ++kt) {
        bf16x8 pa = *(const bf16x8*)(Pl + (i * 16 + lr) * 72 + kt * 32 + lg * 8);
#pragma unroll
        for (int cj = 0; cj < 2; ++cj)
          O[i][cj] = __builtin_amdgcn_mfma_f32_16x16x32_bf16(pa, vb[kt][cj], O[i][cj], 0, 0, 0);
      }
    }
#pragma unroll
    for (int i = 0; i < 4; ++i)
#pragma unroll
      for (int cj = 0; cj < 2; ++cj)
#pragma unroll
        for (int r = 0; r < 4; ++r) {
          int n = i * 16 + lg * 4 + r;
          if (n < 49)
            attn_out[((size_t)w * 49 + n) * 384 + h * 32 + cj * 16 + lr] =
                __float2bfloat16(O[i][cj][r]);
        }
  }
}

extern "C" void kernel_launch(void* const* d_in, const int* in_sizes, int n_in,
                              void* d_out, int out_size, void* d_ws, size_t ws_size,
                              hipStream_t stream) {
  (void)in_sizes; (void)n_in; (void)out_size;
  const float* x     = (const float*)d_in[0];
  const float* g1    = (const float*)d_in[1];
  const float* be1   = (const float*)d_in[2];
  const float* w_qkv = (const float*)d_in[3];
  const float* b_qkv = (const float*)d_in[4];
  const float* rel   = (const float*)d_in[5];
  const float* w_pr  = (const float*)d_in[6];
  const float* b_pr  = (const float*)d_in[7];
  const float* g2    = (const float*)d_in[8];
  const float* be2   = (const float*)d_in[9];
  const float* w1    = (const float*)d_in[10];
  const float* b1    = (const float*)d_in[11];
  const float* w2    = (const float*)d_in[12];
  const float* b2    = (const float*)d_in[13];
  float* out = (float*)d_out;

  if (ws_size < 389545984u) return;

  char* ws = (char*)d_ws;
  bf16* wqkvT = (bf16*)(ws);                     // 1152 x 384
  bf16* wprT  = (bf16*)(ws + 884736);            // 384 x 384
  bf16* w1T   = (bf16*)(ws + 1179648);           // 1536 x 384
  bf16* w2T   = (bf16*)(ws + 2359296);           // 384 x 1536
  float* btbl = (float*)(ws + 3538944);          // 4 x 12 x 49 x 64 f32
  bf16* xw    = (bf16*)(ws + (4u << 20));        // 100352 x 384 bf16 (LN1 / attn out)
  bf16* m_in  = xw;                              // LN2 out reuses xw region
  bf16* qkv   = (bf16*)(ws + (84u << 20));       // padded QKV 302 MB (dead after attn)
  bf16* h1    = (bf16*)(ws + 81264640u);         // FULL 100352 x 1536 bf16 (308 MB)

  cast_transpose<<<dim3((442368 + 255) / 256), 256, 0, stream>>>(w_qkv, wqkvT, 384, 1152);
  cast_transpose<<<dim3((147456 + 255) / 256), 256, 0, stream>>>(w_pr, wprT, 384, 384);
  cast_transpose<<<dim3((589824 + 255) / 256), 256, 0, stream>>>(w1, w1T, 384, 1536);
  cast_transpose<<<dim3((589824 + 255) / 256), 256, 0, stream>>>(w2, w2T, 1536, 384);

  build_bias<<<dim3((4 * 12 * 49 * 64 + 255) / 256), 256, 0, stream>>>(rel, btbl);

  zero_pads<<<dim3((NWIN * 3 * NH * 15 * HD + 255) / 256), 256, 0, stream>>>(qkv);

  ln_kernel<0><<<dim3(NTOK / 4), 256, 0, stream>>>(x, g1, be1, xw);

  // QKV: 784 brows x 9 bcols = 7056
  gemm128<0><<<dim3(7056), 256, 0, stream>>>(xw, wqkvT, 384, 9, 0, b_qkv, nullptr,
                                             (void*)qkv);

  attn_kernel<<<dim3(NWIN), 256, 0, stream>>>(qkv, btbl, xw);

  // proj: 784 x 3 = 2352
  gemm128<1><<<dim3(2352), 256, 0, stream>>>(xw, wprT, 384, 3, 0, b_pr, x, (void*)out);

  ln_kernel<1><<<dim3(NTOK / 4), 256, 0, stream>>>(out, g2, be2, m_in);

  // MLP1 single launch: 784 x 12 = 9408 (fast GELU epilogue)
  gemm128<2><<<dim3(9408), 256, 0, stream>>>(m_in, w1T, 384, 12, 0, b1, nullptr, (void*)h1);

  // MLP2 single launch: 784 x 3 = 2352 (K=1536, streaming A -> 3-stage counted vmcnt)
  gemm3s<<<dim3(2352), 256, 0, stream>>>(h1, w2T, 1536, 3, 0, b2, out, out);
}

// Round 19
// 893.515 us; speedup vs baseline: 1.0594x; 1.0594x over previous
//
#include <hip/hip_runtime.h>
#include <hip/hip_bf16.h>
#include <math.h>

typedef __attribute__((ext_vector_type(8))) short bf16x8;
typedef __attribute__((ext_vector_type(4))) short bf16x4;
typedef __attribute__((ext_vector_type(4))) float f32x4;
typedef __hip_bfloat16 bf16;

#define NH 12
#define HD 32
#define NPAD 64
#define NWIN 2048
#define NTOK 100352
#define HBLK (NPAD*HD)
#define WBLK (3*NH*HBLK)

typedef __attribute__((address_space(3))) const void cv3;

#define STR2(x) #x
#define DSR(dst, base, OFF)                                                  \
  asm volatile("ds_read_b128 %0, %1 offset:" STR2(OFF)                       \
               : "=v"(dst) : "v"(base))

__device__ inline float wave_sum(float v) {
#pragma unroll
  for (int off = 32; off; off >>= 1) v += __shfl_xor(v, off);
  return v;
}

__device__ inline void load_lds16(const bf16* g, bf16* l) {
  __builtin_amdgcn_global_load_lds((const __attribute__((address_space(1))) void*)g,
                                   (__attribute__((address_space(3))) void*)l, 16, 0, 0);
}

__device__ inline short bfbits(float f) {
  bf16 h = __float2bfloat16(f);
  return *(short*)&h;
}

// tanh-form GELU via hardware exp (measured neutral vs erff, kept)
__device__ inline float gelu_fast(float x) {
  float u = x + 0.044715f * x * x * x;
  float a = fminf(1.5957691216057308f * u, 80.0f);
  float e = __expf(a);
  return x * e / (e + 1.0f);
}

// ---------------- weight cast + transpose
__global__ __launch_bounds__(256) void cast_transpose(const float* __restrict__ in,
                                                      bf16* __restrict__ out, int K, int N) {
  int e = blockIdx.x * 256 + threadIdx.x;
  if (e >= K * N) return;
  int n = e / K, k = e - n * K;
  out[e] = __float2bfloat16(in[k * N + n]);
}

// ---------------- bias+mask table: tbl[cls][h][row][64] (cols 49..63 = -1e30).
// NOTE: the -1e30 column mask is what makes qkv pad rows (49-63) not need zeroing:
// K-pads -> masked cols, V-pads -> multiplied by P=0, Q-pads -> discarded rows.
__global__ __launch_bounds__(256) void build_bias(const float* __restrict__ rel,
                                                  float* __restrict__ tbl) {
  int e = blockIdx.x * 256 + threadIdx.x;
  if (e >= 4 * 12 * 49 * 64) return;
  int col = e & 63; int t = e >> 6;
  int row = t % 49; t /= 49;
  int h = t % 12; int cls = t / 12;
  float v;
  if (col >= 49) {
    v = -1e30f;
  } else {
    int py = row / 7, px = row - py * 7;
    int qy = col / 7, qx = col - qy * 7;
    int ridx = (py - qy + 6) * 13 + (px - qx + 6);
    v = rel[ridx * 12 + h];
    int wy7 = cls >> 1, wx7 = cls & 1;
    int ly_r = wy7 ? (py < 4 ? 1 : 2) : 0;
    int lx_r = wx7 ? (px < 4 ? 1 : 2) : 0;
    int ly_c = wy7 ? (qy < 4 ? 1 : 2) : 0;
    int lx_c = wx7 ? (qx < 4 ? 1 : 2) : 0;
    if ((ly_r * 3 + lx_r) != (ly_c * 3 + lx_c)) v += -100.0f;
  }
  tbl[e] = v;
}

// ---------------- LayerNorm
template <int MODE>
__global__ __launch_bounds__(256) void ln_kernel(const float* __restrict__ x,
                                                 const float* __restrict__ g,
                                                 const float* __restrict__ be,
                                                 bf16* __restrict__ out) {
  int wv = threadIdx.x >> 6, lane = threadIdx.x & 63;
  int t = blockIdx.x * 4 + wv;
  size_t src;
  if (MODE == 0) {
    int w = t / 49, n = t - w * 49;
    int b = w >> 6, wi = w & 63;
    int wy = wi >> 3, wx = wi & 7;
    int py = n / 7, px = n - py * 7;
    int rr = wy * 7 + py, cc = wx * 7 + px;
    int ro = rr + 3; if (ro >= 56) ro -= 56;
    int co = cc + 3; if (co >= 56) co -= 56;
    src = (size_t)b * 3136 + ro * 56 + co;
  } else {
    src = (size_t)t;
  }
  const float2* row2 = (const float2*)(x + src * 384);
  float2 v[3]; float s = 0.f;
#pragma unroll
  for (int j = 0; j < 3; ++j) { v[j] = row2[lane + 64 * j]; s += v[j].x + v[j].y; }
  s = wave_sum(s);
  float mu = s * (1.f / 384.f);
  float q = 0.f;
#pragma unroll
  for (int j = 0; j < 3; ++j) {
    float dx = v[j].x - mu, dy = v[j].y - mu;
    q += dx * dx + dy * dy;
  }
  q = wave_sum(q);
  float rs = rsqrtf(q * (1.f / 384.f) + 1e-5f);
  uint* o = (uint*)(out + (size_t)t * 384);
  const float2* g2 = (const float2*)g;
  const float2* b2 = (const float2*)be;
#pragma unroll
  for (int j = 0; j < 3; ++j) {
    int c2 = lane + 64 * j;
    float2 gg = g2[c2], bb = b2[c2];
    float ox = (v[j].x - mu) * rs * gg.x + bb.x;
    float oy = (v[j].y - mu) * rs * gg.y + bb.y;
    o[c2] = (uint)(unsigned short)bfbits(ox) | ((uint)(unsigned short)bfbits(oy) << 16);
  }
}

// ---------------- GEMM for K=384 layers: 128x128, 4 waves, BK=32, 2-stage ring = 32 KB,
// per-iter vmcnt(0) covered by 4 blocks/CU. EPI: 0=QKV scatter, 1=proj+residual+reverse,
// 2=fastGELU->h1
template <int EPI>
__global__ __launch_bounds__(256, 4) void gemm128(const bf16* __restrict__ A,
                                                  const bf16* __restrict__ BT,
                                                  int K, int NCOL, int row0,
                                                  const float* __restrict__ bias,
                                                  const float* __restrict__ extra,
                                                  void* __restrict__ outp) {
  __shared__ __align__(16) bf16 As[2][128 * 32];
  __shared__ __align__(16) bf16 Bs[2][128 * 32];
  int tid = threadIdx.x, lane = tid & 63, wv = tid >> 6;
  int wr = wv >> 1, wc = wv & 1;
  int lr = lane & 15, lg = lane >> 4;

  int nwg = gridDim.x;
  int bid = blockIdx.x;
  int xcd = bid & 7, li = bid >> 3;
  int qq = nwg >> 3, rr8 = nwg & 7;
  int start = xcd * qq + (xcd < rr8 ? xcd : rr8);
  int lin = start + li;
  int brow = lin / NCOL, bcol = lin - brow * NCOL;

  const bf16* Ab = A + (size_t)brow * 128 * K;
  const bf16* Bb = BT + (size_t)bcol * 128 * K;

  int srow = lane >> 2;
  int scol8 = (((lane & 3) ^ ((srow >> 1) & 3)) << 3);
  const bf16* aS = Ab + (size_t)(wv * 32 + srow) * K + scol8;
  const bf16* bS = Bb + (size_t)(wv * 32 + srow) * K + scol8;

  f32x4 acc[4][4] = {};
  int nk = K >> 5;
  int koff = ((lg ^ ((lr >> 1) & 3)) << 3);

#define STAGE(buf)                                                            \
  {                                                                           \
    load_lds16(aS, &As[buf][wv * 1024]);                                      \
    load_lds16(aS + (size_t)16 * K, &As[buf][wv * 1024 + 512]);               \
    load_lds16(bS, &Bs[buf][wv * 1024]);                                      \
    load_lds16(bS + (size_t)16 * K, &Bs[buf][wv * 1024 + 512]);               \
    aS += 32; bS += 32;                                                       \
  }

  STAGE(0);
  asm volatile("s_waitcnt vmcnt(0)" ::: "memory");
  __builtin_amdgcn_s_barrier();

  for (int it = 0; it < nk; ++it) {
    int buf = it & 1;
    if (it + 1 < nk) STAGE(buf ^ 1);
    cv3* pA = (cv3*)&As[buf][(wr * 64 + lr) * 32 + koff];
    cv3* pB = (cv3*)&Bs[buf][(wc * 64 + lr) * 32 + koff];
    bf16x8 a[4], b[4];
    DSR(a[0], pA, 0);
    DSR(b[0], pB, 0); DSR(b[1], pB, 1024); DSR(b[2], pB, 2048); DSR(b[3], pB, 3072);
    DSR(a[1], pA, 1024); DSR(a[2], pA, 2048); DSR(a[3], pA, 3072);
    asm volatile("s_waitcnt lgkmcnt(3)" ::: "memory");
    __builtin_amdgcn_sched_barrier(0);
    __builtin_amdgcn_s_setprio(1);
#pragma unroll
    for (int j = 0; j < 4; ++j)
      acc[0][j] = __builtin_amdgcn_mfma_f32_16x16x32_bf16(b[j], a[0], acc[0][j], 0, 0, 0);
    __builtin_amdgcn_s_setprio(0);
    asm volatile("s_waitcnt lgkmcnt(0)" ::: "memory");
    __builtin_amdgcn_sched_barrier(0);
    __builtin_amdgcn_s_setprio(1);
#pragma unroll
    for (int i = 1; i < 4; ++i)
#pragma unroll
      for (int j = 0; j < 4; ++j)
        acc[i][j] = __builtin_amdgcn_mfma_f32_16x16x32_bf16(b[j], a[i], acc[i][j], 0, 0, 0);
    __builtin_amdgcn_s_setprio(0);
    if (it + 1 < nk) {
      asm volatile("s_waitcnt vmcnt(0)" ::: "memory");
      __builtin_amdgcn_s_barrier();
    }
  }
#undef STAGE

  float4 bias4[4];
#pragma unroll
  for (int j = 0; j < 4; ++j)
    bias4[j] = *(const float4*)(bias + bcol * 128 + wc * 64 + j * 16 + lg * 4);

#pragma unroll
  for (int i = 0; i < 4; ++i) {
    int lrow = brow * 128 + wr * 64 + i * 16 + lr;
    int grow = row0 + lrow;
    int w_ = 0, n_ = 0; size_t tok = 0;
    if (EPI == 0 || EPI == 1) {
      w_ = grow / 49; n_ = grow - w_ * 49;
      if (EPI == 1) {
        int b_ = w_ >> 6, wi = w_ & 63;
        int wy = wi >> 3, wx = wi & 7;
        int py = n_ / 7, px = n_ - py * 7;
        int r2 = wy * 7 + py, c2 = wx * 7 + px;
        int ro = r2 + 3; if (ro >= 56) ro -= 56;
        int co = c2 + 3; if (co >= 56) co -= 56;
        tok = (size_t)b_ * 3136 + ro * 56 + co;
      }
    }
#pragma unroll
    for (int j = 0; j < 4; ++j) {
      int col = bcol * 128 + wc * 64 + j * 16 + lg * 4;
      float v0 = acc[i][j][0] + bias4[j].x;
      float v1 = acc[i][j][1] + bias4[j].y;
      float v2 = acc[i][j][2] + bias4[j].z;
      float v3 = acc[i][j][3] + bias4[j].w;
      if (EPI == 0) {
        int which = (col >= 768) ? 2 : (col >= 384 ? 1 : 0);
        int cc = col - which * 384;
        int hh = cc >> 5, d0 = cc & 31;
        size_t base = (size_t)w_ * WBLK + (size_t)which * NH * HBLK + (size_t)hh * HBLK;
        if (which == 2) {
          bf16* vp = (bf16*)outp + base + (size_t)d0 * NPAD + n_;
          vp[0] = __float2bfloat16(v0);
          vp[NPAD] = __float2bfloat16(v1);
          vp[2 * NPAD] = __float2bfloat16(v2);
          vp[3 * NPAD] = __float2bfloat16(v3);
        } else {
          bf16x4 p = {bfbits(v0), bfbits(v1), bfbits(v2), bfbits(v3)};
          *(bf16x4*)((bf16*)outp + base + (size_t)n_ * HD + d0) = p;
        }
      } else if (EPI == 1) {
        size_t oidx = tok * 384 + col;
        float4 e = *(const float4*)(extra + oidx);
        float4 o = {v0 + e.x, v1 + e.y, v2 + e.z, v3 + e.w};
        *(float4*)((float*)outp + oidx) = o;
      } else {
        bf16x4 p = {bfbits(gelu_fast(v0)), bfbits(gelu_fast(v1)),
                    bfbits(gelu_fast(v2)), bfbits(gelu_fast(v3))};
        *(bf16x4*)((bf16*)outp + (size_t)lrow * 1536 + col) = p;
      }
    }
  }
}

// ---------------- 3-STAGE GEMM for MLP2 (K=1536, streaming HBM-cold A = h1): counted
// vmcnt(4) pipeline, 48 KB, 3 blocks/CU. EPI fixed: out = acc + b2 + x1 -> d_out.
__global__ __launch_bounds__(256, 3) void gemm3s(const bf16* __restrict__ A,
                                                 const bf16* __restrict__ BT,
                                                 int K, int NCOL, int row0,
                                                 const float* __restrict__ bias,
                                                 const float* __restrict__ extra,
                                                 float* __restrict__ outp) {
  __shared__ __align__(16) bf16 As[3][128 * 32];
  __shared__ __align__(16) bf16 Bs[3][128 * 32];
  int tid = threadIdx.x, lane = tid & 63, wv = tid >> 6;
  int wr = wv >> 1, wc = wv & 1;
  int lr = lane & 15, lg = lane >> 4;

  int nwg = gridDim.x;
  int bid = blockIdx.x;
  int xcd = bid & 7, li = bid >> 3;
  int qq = nwg >> 3, rr8 = nwg & 7;
  int start = xcd * qq + (xcd < rr8 ? xcd : rr8);
  int lin = start + li;
  int brow = lin / NCOL, bcol = lin - brow * NCOL;

  const bf16* Ab = A + (size_t)brow * 128 * K;
  const bf16* Bb = BT + (size_t)bcol * 128 * K;

  int srow = lane >> 2;
  int scol8 = (((lane & 3) ^ ((srow >> 1) & 3)) << 3);
  const bf16* aS = Ab + (size_t)(wv * 32 + srow) * K + scol8;
  const bf16* bS = Bb + (size_t)(wv * 32 + srow) * K + scol8;

  f32x4 acc[4][4] = {};
  int nk = K >> 5;
  int koff = ((lg ^ ((lr >> 1) & 3)) << 3);

#define STAGE3(buf)                                                           \
  {                                                                           \
    load_lds16(aS, &As[buf][wv * 1024]);                                      \
    load_lds16(aS + (size_t)16 * K, &As[buf][wv * 1024 + 512]);               \
    load_lds16(bS, &Bs[buf][wv * 1024]);                                      \
    load_lds16(bS + (size_t)16 * K, &Bs[buf][wv * 1024 + 512]);               \
    aS += 32; bS += 32;                                                       \
  }

  STAGE3(0);
  STAGE3(1);
  asm volatile("s_waitcnt vmcnt(4)" ::: "memory");
  __builtin_amdgcn_s_barrier();

  for (int it = 0; it < nk; ++it) {
    int buf = it % 3;
    if (it + 2 < nk) STAGE3((it + 2) % 3);
    cv3* pA = (cv3*)&As[buf][(wr * 64 + lr) * 32 + koff];
    cv3* pB = (cv3*)&Bs[buf][(wc * 64 + lr) * 32 + koff];
    bf16x8 a[4], b[4];
    DSR(a[0], pA, 0);
    DSR(b[0], pB, 0); DSR(b[1], pB, 1024); DSR(b[2], pB, 2048); DSR(b[3], pB, 3072);
    DSR(a[1], pA, 1024); DSR(a[2], pA, 2048); DSR(a[3], pA, 3072);
    asm volatile("s_waitcnt lgkmcnt(3)" ::: "memory");
    __builtin_amdgcn_sched_barrier(0);
    __builtin_amdgcn_s_setprio(1);
#pragma unroll
    for (int j = 0; j < 4; ++j)
      acc[0][j] = __builtin_amdgcn_mfma_f32_16x16x32_bf16(b[j], a[0], acc[0][j], 0, 0, 0);
    __builtin_amdgcn_s_setprio(0);
    asm volatile("s_waitcnt lgkmcnt(0)" ::: "memory");
    __builtin_amdgcn_sched_barrier(0);
    __builtin_amdgcn_s_setprio(1);
#pragma unroll
    for (int i = 1; i < 4; ++i)
#pragma unroll
      for (int j = 0; j < 4; ++j)
        acc[i][j] = __builtin_amdgcn_mfma_f32_16x16x32_bf16(b[j], a[i], acc[i][j], 0, 0, 0);
    __builtin_amdgcn_s_setprio(0);
    if (it + 1 < nk) {
      if (it + 2 < nk)
        asm volatile("s_waitcnt vmcnt(4)" ::: "memory");
      else
        asm volatile("s_waitcnt vmcnt(0)" ::: "memory");
      __builtin_amdgcn_s_barrier();
    }
  }
#undef STAGE3

  float4 bias4[4];
#pragma unroll
  for (int j = 0; j < 4; ++j)
    bias4[j] = *(const float4*)(bias + bcol * 128 + wc * 64 + j * 16 + lg * 4);

#pragma unroll
  for (int i = 0; i < 4; ++i) {
    int grow = row0 + brow * 128 + wr * 64 + i * 16 + lr;
#pragma unroll
    for (int j = 0; j < 4; ++j) {
      int col = bcol * 128 + wc * 64 + j * 16 + lg * 4;
      size_t oidx = (size_t)grow * 384 + col;
      float4 e = *(const float4*)(extra + oidx);
      float4 o = {acc[i][j][0] + bias4[j].x + e.x, acc[i][j][1] + bias4[j].y + e.y,
                  acc[i][j][2] + bias4[j].z + e.z, acc[i][j][3] + bias4[j].w + e.w};
      *(float4*)(outp + oidx) = o;
    }
  }
}

// ---------------- windowed attention: 1 block per window, 4 waves x 3 heads.
// Pad rows 49-63 of qkv hold arbitrary FINITE garbage (prior h1/qkv values or 0xAA
// poison ~ -3e-13): K-pads masked by tbl's -1e30 cols, V-pads multiplied by P=0,
// Q-pads discarded by the n<49 store guard. No zeroing needed.
__global__ __launch_bounds__(256) void attn_kernel(const bf16* __restrict__ qkv,
                                                   const float* __restrict__ tbl,
                                                   bf16* __restrict__ attn_out) {
  __shared__ __align__(16) bf16 P[4][64 * 72];
  int wv = threadIdx.x >> 6, lane = threadIdx.x & 63;
  int lr = lane & 15, lg = lane >> 4;
  int w = blockIdx.x;
  int wi = w & 63, wy = wi >> 3, wx = wi & 7;
  int cls = ((wy == 7) ? 2 : 0) | ((wx == 7) ? 1 : 0);
  const bf16* base = qkv + (size_t)w * WBLK;
  bf16* Pl = &P[wv][0];
  const float scale = 0.17677669529663689f;

  for (int hh = 0; hh < 3; ++hh) {
    int h = wv + hh * 4;
    const bf16* Q  = base + (size_t)h * HBLK;
    const bf16* Kp = base + (size_t)(NH + h) * HBLK;
    const bf16* Vt = base + (size_t)(2 * NH + h) * HBLK;
    const float* tb = tbl + (size_t)(cls * 12 + h) * 49 * 64;

    bf16x8 qa[4], kb[4];
#pragma unroll
    for (int t = 0; t < 4; ++t) {
      qa[t] = *(const bf16x8*)(Q  + (t * 16 + lr) * 32 + lg * 8);
      kb[t] = *(const bf16x8*)(Kp + (t * 16 + lr) * 32 + lg * 8);
    }
    f32x4 S[4][4] = {};
#pragma unroll
    for (int i = 0; i < 4; ++i)
#pragma unroll
      for (int j = 0; j < 4; ++j)
        S[i][j] = __builtin_amdgcn_mfma_f32_16x16x32_bf16(qa[i], kb[j], S[i][j], 0, 0, 0);

#pragma unroll
    for (int i = 0; i < 4; ++i) {
#pragma unroll
      for (int r = 0; r < 4; ++r) {
        int row = i * 16 + lg * 4 + r;
        const float* trow = tb + (row < 49 ? row : 0) * 64;
        float sv[4]; float m = -1e30f;
#pragma unroll
        for (int j = 0; j < 4; ++j) {
          float s = S[i][j][r] * scale + trow[j * 16 + lr];
          sv[j] = s;
          m = fmaxf(m, s);
        }
        m = fmaxf(m, __shfl_xor(m, 1));
        m = fmaxf(m, __shfl_xor(m, 2));
        m = fmaxf(m, __shfl_xor(m, 4));
        m = fmaxf(m, __shfl_xor(m, 8));
        float ev[4]; float sum = 0.f;
#pragma unroll
        for (int j = 0; j < 4; ++j) { ev[j] = __expf(sv[j] - m); sum += ev[j]; }
        sum += __shfl_xor(sum, 1);
        sum += __shfl_xor(sum, 2);
        sum += __shfl_xor(sum, 4);
        sum += __shfl_xor(sum, 8);
        float inv = 1.0f / sum;
#pragma unroll
        for (int j = 0; j < 4; ++j)
          Pl[row * 72 + j * 16 + lr] = __float2bfloat16(ev[j] * inv);
      }
    }

    bf16x8 vb[2][2];
#pragma unroll
    for (int kt = 0; kt < 2; ++kt)
#pragma unroll
      for (int cj = 0; cj < 2; ++cj)
        vb[kt][cj] = *(const bf16x8*)(Vt + (cj * 16 + lr) * 64 + kt * 32 + lg * 8);
    f32x4 O[4][2] = {};
#pragma unroll
    for (int i = 0; i < 4; ++i) {
#pragma unroll
      for (int kt = 0; kt < 2; ++kt) {
        bf16x8 pa = *(const bf16x8*)(Pl + (i * 16 + lr) * 72 + kt * 32 + lg * 8);
#pragma unroll
        for (int cj = 0; cj < 2; ++cj)
          O[i][cj] = __builtin_amdgcn_mfma_f32_16x16x32_bf16(pa, vb[kt][cj], O[i][cj], 0, 0, 0);
      }
    }
#pragma unroll
    for (int i = 0; i < 4; ++i)
#pragma unroll
      for (int cj = 0; cj < 2; ++cj)
#pragma unroll
        for (int r = 0; r < 4; ++r) {
          int n = i * 16 + lg * 4 + r;
          if (n < 49)
            attn_out[((size_t)w * 49 + n) * 384 + h * 32 + cj * 16 + lr] =
                __float2bfloat16(O[i][cj][r]);
        }
  }
}

extern "C" void kernel_launch(void* const* d_in, const int* in_sizes, int n_in,
                              void* d_out, int out_size, void* d_ws, size_t ws_size,
                              hipStream_t stream) {
  (void)in_sizes; (void)n_in; (void)out_size;
  const float* x     = (const float*)d_in[0];
  const float* g1    = (const float*)d_in[1];
  const float* be1   = (const float*)d_in[2];
  const float* w_qkv = (const float*)d_in[3];
  const float* b_qkv = (const float*)d_in[4];
  const float* rel   = (const float*)d_in[5];
  const float* w_pr  = (const float*)d_in[6];
  const float* b_pr  = (const float*)d_in[7];
  const float* g2    = (const float*)d_in[8];
  const float* be2   = (const float*)d_in[9];
  const float* w1    = (const float*)d_in[10];
  const float* b1    = (const float*)d_in[11];
  const float* w2    = (const float*)d_in[12];
  const float* b2    = (const float*)d_in[13];
  float* out = (float*)d_out;

  if (ws_size < 389545984u) return;

  char* ws = (char*)d_ws;
  bf16* wqkvT = (bf16*)(ws);                     // 1152 x 384
  bf16* wprT  = (bf16*)(ws + 884736);            // 384 x 384
  bf16* w1T   = (bf16*)(ws + 1179648);           // 1536 x 384
  bf16* w2T   = (bf16*)(ws + 2359296);           // 384 x 1536
  float* btbl = (float*)(ws + 3538944);          // 4 x 12 x 49 x 64 f32
  bf16* xw    = (bf16*)(ws + (4u << 20));        // 100352 x 384 bf16 (LN1 / attn out)
  bf16* m_in  = xw;                              // LN2 out reuses xw region
  bf16* qkv   = (bf16*)(ws + (84u << 20));       // padded QKV 302 MB (pads never zeroed;
                                                 // finite garbage is masked in attn)
  bf16* h1    = (bf16*)(ws + 81264640u);         // FULL 100352 x 1536 bf16 (308 MB)

  cast_transpose<<<dim3((442368 + 255) / 256), 256, 0, stream>>>(w_qkv, wqkvT, 384, 1152);
  cast_transpose<<<dim3((147456 + 255) / 256), 256, 0, stream>>>(w_pr, wprT, 384, 384);
  cast_transpose<<<dim3((589824 + 255) / 256), 256, 0, stream>>>(w1, w1T, 384, 1536);
  cast_transpose<<<dim3((589824 + 255) / 256), 256, 0, stream>>>(w2, w2T, 1536, 384);

  build_bias<<<dim3((4 * 12 * 49 * 64 + 255) / 256), 256, 0, stream>>>(rel, btbl);

  ln_kernel<0><<<dim3(NTOK / 4), 256, 0, stream>>>(x, g1, be1, xw);

  // QKV: 784 brows x 9 bcols = 7056
  gemm128<0><<<dim3(7056), 256, 0, stream>>>(xw, wqkvT, 384, 9, 0, b_qkv, nullptr,
                                             (void*)qkv);

  attn_kernel<<<dim3(NWIN), 256, 0, stream>>>(qkv, btbl, xw);

  // proj: 784 x 3 = 2352
  gemm128<1><<<dim3(2352), 256, 0, stream>>>(xw, wprT, 384, 3, 0, b_pr, x, (void*)out);

  ln_kernel<1><<<dim3(NTOK / 4), 256, 0, stream>>>(out, g2, be2, m_in);

  // MLP1 single launch: 784 x 12 = 9408 (fast GELU epilogue)
  gemm128<2><<<dim3(9408), 256, 0, stream>>>(m_in, w1T, 384, 12, 0, b1, nullptr, (void*)h1);

  // MLP2 single launch: 784 x 3 = 2352 (K=1536, streaming A -> 3-stage counted vmcnt)
  gemm3s<<<dim3(2352), 256, 0, stream>>>(h1, w2T, 1536, 3, 0, b2, out, out);
}